// Round 1
// 672.825 us; speedup vs baseline: 1.0011x; 1.0011x over previous
//
#include <hip/hip_runtime.h>
#include <cmath>

#define BATCH 64
#define NCTX 2048
#define DIM 1024
#define CHUNKS 16
#define ROWS_PER_CHUNK (NCTX / CHUNKS)     // 128
#define ROWS_PER_WAVE (ROWS_PER_CHUNK / 4) // 32

typedef float f4_t __attribute__((ext_vector_type(4)));

// ---------------- Phase 1: flash-style scores + online softmax partials ---------------
// grid = BATCH*CHUNKS = 1024 blocks, 256 threads (4 waves).
// Each wave: 32 rows, 4 rows/iter, ping-pong double-buffered so next iteration's
// 16 dwordx4 loads are in flight during current iteration's compute.
__global__ __launch_bounds__(256) void attn_phase1(
    const float* __restrict__ q,     // [B, 1, D]
    const float* __restrict__ ctx,   // [B, N, D]
    float* __restrict__ scores,      // [B, N]      (raw logits)
    float* __restrict__ part_m,      // [B, CHUNKS]
    float* __restrict__ part_l,      // [B, CHUNKS]
    float* __restrict__ part_o)      // [B, CHUNKS, D]
{
    const int blk  = blockIdx.x;
    const int b    = blk / CHUNKS;
    const int c    = blk % CHUNKS;
    const int tid  = threadIdx.x;
    const int wave = tid >> 6;
    const int lane = tid & 63;

    // q fragment: lane covers elements lane*4 + 256*j + {0..3}, j=0..3
    f4_t qf[4];
    const float* qb = q + (size_t)b * DIM;
    #pragma unroll
    for (int j = 0; j < 4; ++j)
        qf[j] = *reinterpret_cast<const f4_t*>(qb + lane * 4 + 256 * j);

    float m = -INFINITY, l = 0.f;
    f4_t o[4];
    #pragma unroll
    for (int j = 0; j < 4; ++j) o[j] = (f4_t)(0.f);

    const int row0 = c * ROWS_PER_CHUNK + wave * ROWS_PER_WAVE;
    const float* cb = ctx + (size_t)b * NCTX * DIM;
    float* sc = scores + (size_t)b * NCTX;

    auto loadrows = [&](f4_t (&cf)[4][4], int i) {
        #pragma unroll
        for (int r = 0; r < 4; ++r) {
            const float* cr = cb + (size_t)(row0 + i + r) * DIM + lane * 4;
            #pragma unroll
            for (int j = 0; j < 4; ++j)
                cf[r][j] = __builtin_nontemporal_load(
                    reinterpret_cast<const f4_t*>(cr + 256 * j));
        }
    };

    auto process = [&](f4_t (&cf)[4][4], int i) {
        float s[4];
        #pragma unroll
        for (int r = 0; r < 4; ++r) {
            float d0 = qf[0].x * cf[r][0].x + qf[0].y * cf[r][0].y
                     + qf[0].z * cf[r][0].z + qf[0].w * cf[r][0].w;
            float d1 = qf[1].x * cf[r][1].x + qf[1].y * cf[r][1].y
                     + qf[1].z * cf[r][1].z + qf[1].w * cf[r][1].w;
            float d2 = qf[2].x * cf[r][2].x + qf[2].y * cf[r][2].y
                     + qf[2].z * cf[r][2].z + qf[2].w * cf[r][2].w;
            float d3 = qf[3].x * cf[r][3].x + qf[3].y * cf[r][3].y
                     + qf[3].z * cf[r][3].z + qf[3].w * cf[r][3].w;
            s[r] = (d0 + d1) + (d2 + d3);
        }

        // four independent 64-lane butterflies (latency overlaps 4-way)
        #pragma unroll
        for (int off = 32; off >= 1; off >>= 1) {
            s[0] += __shfl_xor(s[0], off, 64);
            s[1] += __shfl_xor(s[1], off, 64);
            s[2] += __shfl_xor(s[2], off, 64);
            s[3] += __shfl_xor(s[3], off, 64);
        }

        {
            float sv = (lane == 1) ? s[1] : (lane == 2) ? s[2]
                     : (lane == 3) ? s[3] : s[0];
            if (lane < 4) sc[row0 + i + lane] = sv;
        }

        // wave-uniform rare rescale (s[] uniform after full butterfly)
        const float mx = fmaxf(fmaxf(s[0], s[1]), fmaxf(s[2], s[3]));
        const float m_new = fmaxf(m, mx);
        if (m_new > m) {
            const float a = __expf(m - m_new);
            l *= a;
            #pragma unroll
            for (int j = 0; j < 4; ++j) o[j] *= a;
            m = m_new;
        }
        const float p0 = __expf(s[0] - m);
        const float p1 = __expf(s[1] - m);
        const float p2 = __expf(s[2] - m);
        const float p3 = __expf(s[3] - m);
        l += (p0 + p1) + (p2 + p3);
        #pragma unroll
        for (int j = 0; j < 4; ++j) {
            o[j].x += p0 * cf[0][j].x + p1 * cf[1][j].x
                    + p2 * cf[2][j].x + p3 * cf[3][j].x;
            o[j].y += p0 * cf[0][j].y + p1 * cf[1][j].y
                    + p2 * cf[2][j].y + p3 * cf[3][j].y;
            o[j].z += p0 * cf[0][j].z + p1 * cf[1][j].z
                    + p2 * cf[2][j].z + p3 * cf[3][j].z;
            o[j].w += p0 * cf[0][j].w + p1 * cf[1][j].w
                    + p2 * cf[2][j].w + p3 * cf[3][j].w;
        }
    };

    // ping-pong: prefetch next 4 rows while computing current 4 (static indexing)
    f4_t cfA[4][4], cfB[4][4];
    loadrows(cfA, 0);
    #pragma unroll
    for (int ii = 0; ii < 8; ++ii) {
        if (ii & 1) {
            if (ii < 7) loadrows(cfA, (ii + 1) * 4);
            process(cfB, ii * 4);
        } else {
            if (ii < 7) loadrows(cfB, (ii + 1) * 4);
            process(cfA, ii * 4);
        }
    }

    // ---- combine the 4 waves of this block ----
    __shared__ float wm[4], wl[4];
    __shared__ float o_lds[4 * DIM];
    if (lane == 0) { wm[wave] = m; wl[wave] = l; }
    __syncthreads();

    const float Mb = fmaxf(fmaxf(wm[0], wm[1]), fmaxf(wm[2], wm[3]));
    float Lb = 0.f;
    #pragma unroll
    for (int w = 0; w < 4; ++w) Lb += wl[w] * __expf(wm[w] - Mb);

    const float aw = __expf(m - Mb);
    #pragma unroll
    for (int j = 0; j < 4; ++j) {
        f4_t t = o[j] * aw;
        *reinterpret_cast<f4_t*>(&o_lds[wave * DIM + lane * 4 + 256 * j]) = t;
    }
    __syncthreads();

    {
        const int e = tid * 4;
        f4_t s0 = *reinterpret_cast<const f4_t*>(&o_lds[0 * DIM + e]);
        f4_t s1 = *reinterpret_cast<const f4_t*>(&o_lds[1 * DIM + e]);
        f4_t s2 = *reinterpret_cast<const f4_t*>(&o_lds[2 * DIM + e]);
        f4_t s3 = *reinterpret_cast<const f4_t*>(&o_lds[3 * DIM + e]);
        f4_t r = (s0 + s1) + (s2 + s3);
        *reinterpret_cast<f4_t*>(&part_o[((size_t)b * CHUNKS + c) * DIM + e]) = r;
    }
    if (tid == 0) {
        part_m[b * CHUNKS + c] = Mb;
        part_l[b * CHUNKS + c] = Lb;
    }
}

// ---------------- Phase 2: combine chunk partials -> mix; write attn -----------------
// grid = BATCH*4 = 256 blocks, 256 threads. Each block: D/4 mix elems + N/4 attn elems.
__global__ __launch_bounds__(256) void attn_phase2(
    const float* __restrict__ scores,
    const float* __restrict__ part_m,
    const float* __restrict__ part_l,
    const float* __restrict__ part_o,
    float* __restrict__ mix,        // [B, D] workspace
    float* __restrict__ attn_out)   // d_out + B*D, [B, N]
{
    const int b    = blockIdx.x >> 2;
    const int part = blockIdx.x & 3;
    const int tid  = threadIdx.x;

    float M = -INFINITY;
    #pragma unroll
    for (int i = 0; i < CHUNKS; ++i) M = fmaxf(M, part_m[b * CHUNKS + i]);

    float w[CHUNKS];
    float L = 0.f;
    #pragma unroll
    for (int i = 0; i < CHUNKS; ++i) {
        w[i] = __expf(part_m[b * CHUNKS + i] - M);
        L += part_l[b * CHUNKS + i] * w[i];
    }
    const float invL = 1.f / L;

    // mix slice: 256 consecutive elements
    {
        const int e = part * 256 + tid;
        float acc = 0.f;
        #pragma unroll
        for (int i = 0; i < CHUNKS; ++i)
            acc += part_o[((size_t)b * CHUNKS + i) * DIM + e] * w[i];
        mix[(size_t)b * DIM + e] = acc * invL;
    }

    // attn slice: 512 consecutive elements
    #pragma unroll
    for (int t = 0; t < 2; ++t) {
        const int n = part * 512 + t * 256 + tid;
        attn_out[(size_t)b * NCTX + n] =
            __expf(scores[(size_t)b * NCTX + n] - M) * invL;
    }
}

// ---------------- Phase 3: out = tanh([mix, q] @ W^T + bias) --------------------------
// BT=8 (halves W traffic vs BT=4: 128->64 MB), DT=16.
// grid = (D/16) * (B/8) = 64*8 = 512 blocks, 256 threads. LDS comb[8][2048] = 64 KB.
// Blocks sharing a W d-slice are 64 apart -> same XCD under %8 round-robin -> W slice
// (128 KB) stays resident in that XCD's L2; per-XCD W footprint 1 MB < 4 MB.
#define BT3 8
#define DT3 16
__global__ __launch_bounds__(256) void attn_phase3(
    const float* __restrict__ mix,   // [B, D]
    const float* __restrict__ q,     // [B, 1, D]
    const float* __restrict__ W,     // [D, 2D]
    const float* __restrict__ bias,  // [D]
    float* __restrict__ out)         // d_out, [B, D]
{
    const int d_chunk = blockIdx.x % (DIM / DT3);   // 64
    const int b_chunk = blockIdx.x / (DIM / DT3);   // 8
    const int d0 = d_chunk * DT3;
    const int b0 = b_chunk * BT3;
    const int tid  = threadIdx.x;
    const int wave = tid >> 6;
    const int lane = tid & 63;

    __shared__ float comb[BT3 * 2 * DIM];   // 8 * 2048 floats = 64 KB

    // vectorized staging: 4096 f4 elements, 16 per thread
    {
        const f4_t* mix4 = reinterpret_cast<const f4_t*>(mix);
        const f4_t* q4   = reinterpret_cast<const f4_t*>(q);
        f4_t* comb4      = reinterpret_cast<f4_t*>(comb);
        for (int i = tid; i < BT3 * 2 * DIM / 4; i += 256) {
            const int bl = i >> 9;          // / 512 f4 per batch-row
            const int e4 = i & 511;
            comb4[i] = (e4 < 256) ? mix4[(size_t)(b0 + bl) * 256 + e4]
                                  : q4[(size_t)(b0 + bl) * 256 + (e4 - 256)];
        }
    }
    __syncthreads();

    const int dg = d0 + wave * 4;   // 4 output d's per wave
    float acc[4][BT3];
    #pragma unroll
    for (int di = 0; di < 4; ++di)
        #pragma unroll
        for (int bl = 0; bl < BT3; ++bl) acc[di][bl] = 0.f;

    #pragma unroll 2
    for (int kk = 0; kk < 2 * DIM; kk += 256) {
        f4_t wv[4];
        #pragma unroll
        for (int di = 0; di < 4; ++di)
            wv[di] = *reinterpret_cast<const f4_t*>(
                W + (size_t)(dg + di) * (2 * DIM) + kk + lane * 4);
        #pragma unroll
        for (int bl = 0; bl < BT3; ++bl) {
            f4_t cv = *reinterpret_cast<const f4_t*>(
                &comb[bl * 2 * DIM + kk + lane * 4]);
            #pragma unroll
            for (int di = 0; di < 4; ++di) {
                acc[di][bl] += wv[di].x * cv.x;
                acc[di][bl] += wv[di].y * cv.y;
                acc[di][bl] += wv[di].z * cv.z;
                acc[di][bl] += wv[di].w * cv.w;
            }
        }
    }

    float myval = 0.f;
    #pragma unroll
    for (int di = 0; di < 4; ++di) {
        #pragma unroll
        for (int bl = 0; bl < BT3; ++bl) {
            float v = acc[di][bl];
            #pragma unroll
            for (int off = 32; off >= 1; off >>= 1)
                v += __shfl_xor(v, off, 64);
            if (lane == di * BT3 + bl) myval = v;
        }
    }
    if (lane < 32) {
        const int di = lane >> 3;
        const int bl = lane & 7;
        const int d  = dg + di;
        out[(size_t)(b0 + bl) * DIM + d] = tanhf(myval + bias[d]);
    }
}

extern "C" void kernel_launch(void* const* d_in, const int* in_sizes, int n_in,
                              void* d_out, int out_size, void* d_ws, size_t ws_size,
                              hipStream_t stream) {
    const float* q    = (const float*)d_in[0];   // output, [B,1,D]
    const float* ctx  = (const float*)d_in[1];   // context, [B,N,D]
    const float* W    = (const float*)d_in[2];   // W_out, [D, 2D]
    const float* bias = (const float*)d_in[3];   // b_out, [D]

    float* out_main = (float*)d_out;                         // [B, D]
    float* attn_out = (float*)d_out + (size_t)BATCH * DIM;   // [B, N]

    // workspace layout (floats): scores | part_m | part_l | part_o | mix  (~5 MB)
    float* ws      = (float*)d_ws;
    float* scores  = ws;                                    // B*N       = 131072
    float* part_m  = scores + (size_t)BATCH * NCTX;         // B*CHUNKS  = 1024
    float* part_l  = part_m + BATCH * CHUNKS;               // 1024
    float* part_o  = part_l + BATCH * CHUNKS;               // B*CHUNKS*D = 1048576
    float* mix     = part_o + (size_t)BATCH * CHUNKS * DIM; // B*D = 65536

    attn_phase1<<<BATCH * CHUNKS, 256, 0, stream>>>(q, ctx, scores,
                                                    part_m, part_l, part_o);
    attn_phase2<<<BATCH * 4, 256, 0, stream>>>(scores, part_m, part_l, part_o,
                                               mix, attn_out);
    attn_phase3<<<(DIM / DT3) * (BATCH / BT3), 256, 0, stream>>>(mix, q, W, bias,
                                                                 out_main);
}